// Round 1
// baseline (8185.078 us; speedup 1.0000x reference)
//
#include <hip/hip_runtime.h>
#include <hip/hip_bf16.h>
#include <math.h>

#define EPS 1e-15f

// Per-edge: msg = log1p(EPS - w*x[row]); atomicAdd(agg[col], msg)
// 4 edges per thread via int4/float4 loads (row/col/w contiguous).
__global__ void ic_edge_kernel(const int4* __restrict__ row4,
                               const int4* __restrict__ col4,
                               const float4* __restrict__ w4,
                               const float* __restrict__ x,
                               float* __restrict__ agg,
                               int e4) {
    int i = blockIdx.x * blockDim.x + threadIdx.x;
    int stride = gridDim.x * blockDim.x;
    for (; i < e4; i += stride) {
        int4   rr = row4[i];
        int4   cc = col4[i];
        float4 ww = w4[i];
        float m0 = log1pf(EPS - ww.x * x[rr.x]);
        float m1 = log1pf(EPS - ww.y * x[rr.y]);
        float m2 = log1pf(EPS - ww.z * x[rr.z]);
        float m3 = log1pf(EPS - ww.w * x[rr.w]);
        atomicAdd(&agg[cc.x], m0);
        atomicAdd(&agg[cc.y], m1);
        atomicAdd(&agg[cc.z], m2);
        atomicAdd(&agg[cc.w], m3);
    }
}

// Per-node update. Consumes agg[i] and re-zeros it for the next step.
__global__ void ic_node_kernel(float* __restrict__ s,
                               float* __restrict__ x,
                               float* __restrict__ r,
                               float* __restrict__ agg,
                               int n) {
    int i = blockIdx.x * blockDim.x + threadIdx.x;
    if (i < n) {
        float q  = expf(agg[i]);
        agg[i]   = 0.0f;               // ready for next step's scatter
        float sv = s[i];
        float xv = x[i];
        r[i]    += xv;                 // r_new = r + x_old
        x[i]     = sv * (1.0f - q);    // x_new = s_old * (1-q)
        s[i]     = sv * q;             // s_new = s_old * q
    }
}

// s = 1 - x0, x = x0, r = 0, agg = 0
__global__ void ic_init_kernel(const float* __restrict__ x0,
                               float* __restrict__ s,
                               float* __restrict__ x,
                               float* __restrict__ r,
                               float* __restrict__ agg,
                               int n) {
    int i = blockIdx.x * blockDim.x + threadIdx.x;
    if (i < n) {
        float v = x0[i];
        s[i]   = 1.0f - v;
        x[i]   = v;
        r[i]   = 0.0f;
        agg[i] = 0.0f;
    }
}

extern "C" void kernel_launch(void* const* d_in, const int* in_sizes, int n_in,
                              void* d_out, int out_size, void* d_ws, size_t ws_size,
                              hipStream_t stream) {
    const int*   ei = (const int*)d_in[0];     // [2, E] flattened: row then col
    const float* w  = (const float*)d_in[1];   // [E]
    const float* x0 = (const float*)d_in[2];   // [N]

    const int E = in_sizes[0] / 2;
    const int N = in_sizes[2];

    const int* row = ei;
    const int* col = ei + E;

    float* s   = (float*)d_out;        // [0, N)
    float* x   = s + N;                // [N, 2N)
    float* r   = s + 2 * N;            // [2N, 3N)
    float* agg = (float*)d_ws;         // N floats of scratch

    const int nodeBlocks = (N + 255) / 256;
    ic_init_kernel<<<nodeBlocks, 256, 0, stream>>>(x0, s, x, r, agg, N);

    const int e4 = E / 4;              // E = 16,000,000 -> divisible by 4
    const int edgeBlocks = 2048;       // 256 CUs x 8 blocks, grid-stride

    for (int step = 0; step < 10; ++step) {
        ic_edge_kernel<<<edgeBlocks, 256, 0, stream>>>(
            (const int4*)row, (const int4*)col, (const float4*)w, x, agg, e4);
        ic_node_kernel<<<nodeBlocks, 256, 0, stream>>>(s, x, r, agg, N);
    }
}

// Round 2
// 1521.078 us; speedup vs baseline: 5.3811x; 5.3811x over previous
//
#include <hip/hip_runtime.h>
#include <hip/hip_bf16.h>
#include <math.h>

typedef unsigned int u32;
typedef unsigned long long u64;

#define EPS 1e-15f
#define GC 1024                 // blocks/chunks for count & scatter
#define NPB 64                  // nodes per bucket
#define NPB_SHIFT 6

// ============================ Phase A: bucket sort ============================

// Per-block histogram of col>>6 over a contiguous edge chunk.
__global__ void ic_count_kernel(const int* __restrict__ col, int E, int B,
                                u32* __restrict__ cnt /*[GC][B]*/) {
    extern __shared__ u32 scnt[];
    const int blk = blockIdx.x;
    for (int b = threadIdx.x; b < B; b += blockDim.x) scnt[b] = 0;
    __syncthreads();
    const int chunk = (E + GC - 1) / GC;
    const int s = blk * chunk, e = min(E, s + chunk);
    for (int i = s + threadIdx.x; i < e; i += blockDim.x)
        atomicAdd(&scnt[col[i] >> NPB_SHIFT], 1u);
    __syncthreads();
    for (int b = threadIdx.x; b < B; b += blockDim.x)
        cnt[(size_t)blk * B + b] = scnt[b];
}

// For each bucket b: exclusive scan cnt[0..GC)[b] in place, total -> totals[b].
__global__ void ic_scan_bucket_kernel(u32* __restrict__ cnt, int B,
                                      u32* __restrict__ totals) {
    __shared__ u32 vals[GC];
    __shared__ u32 parts[256];
    const int b = blockIdx.x;
    const int t = threadIdx.x;
    for (int k = t; k < GC; k += blockDim.x)
        vals[k] = cnt[(size_t)k * B + b];
    __syncthreads();
    const int bi = t * 4;
    u32 l0 = vals[bi], l1 = vals[bi + 1], l2 = vals[bi + 2], l3 = vals[bi + 3];
    parts[t] = l0 + l1 + l2 + l3;
    __syncthreads();
    if (t == 0) {
        u32 run = 0;
        for (int k = 0; k < 256; ++k) { u32 v = parts[k]; parts[k] = run; run += v; }
        totals[b] = run;
    }
    __syncthreads();
    u32 run = parts[t];
    vals[bi] = run;     run += l0;
    vals[bi + 1] = run; run += l1;
    vals[bi + 2] = run; run += l2;
    vals[bi + 3] = run;
    __syncthreads();
    for (int k = t; k < GC; k += blockDim.x)
        cnt[(size_t)k * B + b] = vals[k];
}

// Single-block exclusive scan of totals[B] -> base[B+1].
__global__ void ic_scan_base_kernel(const u32* __restrict__ totals, int B,
                                    u32* __restrict__ base, int E) {
    __shared__ u32 parts[256];
    const int t = threadIdx.x;
    const int CH = (B + 255) / 256;
    const int s = t * CH, e = min(B, s + CH);
    u32 sum = 0;
    for (int i = s; i < e; ++i) sum += totals[i];
    parts[t] = sum;
    __syncthreads();
    if (t == 0) {
        u32 run = 0;
        for (int k = 0; k < 256; ++k) { u32 v = parts[k]; parts[k] = run; run += v; }
    }
    __syncthreads();
    u32 run = parts[t];
    for (int i = s; i < e; ++i) { base[i] = run; run += totals[i]; }
    if (t == 0) base[B] = (u32)E;
}

// Scatter edges to bucket-sorted record array: rec = (f32bits(w)<<32)|(row<<6|col&63)
__global__ void ic_scatter_kernel(const int* __restrict__ row,
                                  const int* __restrict__ col,
                                  const float* __restrict__ w,
                                  const u32* __restrict__ cnt,
                                  const u32* __restrict__ base,
                                  int E, int B,
                                  u64* __restrict__ rec) {
    extern __shared__ u32 cursor[];
    const int blk = blockIdx.x;
    for (int b = threadIdx.x; b < B; b += blockDim.x)
        cursor[b] = cnt[(size_t)blk * B + b] + base[b];
    __syncthreads();
    const int chunk = (E + GC - 1) / GC;
    const int s = blk * chunk, e = min(E, s + chunk);
    for (int i = s + threadIdx.x; i < e; i += blockDim.x) {
        const int c = col[i];
        const int b = c >> NPB_SHIFT;
        const u32 pos = atomicAdd(&cursor[b], 1u);
        const u32 rc = ((u32)row[i] << NPB_SHIFT) | (u32)(c & (NPB - 1));
        rec[pos] = ((u64)__float_as_uint(w[i]) << 32) | rc;
    }
}

// ==================== Phase B: fused edge-aggregate + node update ====================

__global__ void ic_step_kernel(const u64* __restrict__ rec,
                               const u32* __restrict__ base,
                               const float* __restrict__ xin,
                               float* __restrict__ xout,
                               float* __restrict__ s,
                               float* __restrict__ r,
                               int N) {
    __shared__ float lagg[NPB];
    const int b = blockIdx.x;
    if (threadIdx.x < NPB) lagg[threadIdx.x] = 0.0f;
    __syncthreads();
    const u32 st = base[b], en = base[b + 1];
    for (u32 i = st + threadIdx.x; i < en; i += blockDim.x) {
        const u64 rv = rec[i];
        const u32 rc = (u32)rv;
        const float wv = __uint_as_float((u32)(rv >> 32));
        const float xv = xin[rc >> NPB_SHIFT];
        atomicAdd(&lagg[rc & (NPB - 1)], log1pf(EPS - wv * xv));
    }
    __syncthreads();
    const int j = b * NPB + threadIdx.x;
    if (threadIdx.x < NPB && j < N) {
        const float q = expf(lagg[threadIdx.x]);
        const float sv = s[j];
        const float xo = xin[j];
        r[j] += xo;
        xout[j] = sv * (1.0f - q);
        s[j] = sv * q;
    }
}

// s = 1-x0, x = x0, r = 0
__global__ void ic_init_kernel(const float* __restrict__ x0,
                               float* __restrict__ s,
                               float* __restrict__ x,
                               float* __restrict__ r,
                               int n) {
    const int i = blockIdx.x * blockDim.x + threadIdx.x;
    if (i < n) {
        const float v = x0[i];
        s[i] = 1.0f - v;
        x[i] = v;
        r[i] = 0.0f;
    }
}

// ======================= Fallback (round-1 atomic path) =======================

__global__ void ic_edge_kernel(const int4* __restrict__ row4,
                               const int4* __restrict__ col4,
                               const float4* __restrict__ w4,
                               const float* __restrict__ x,
                               float* __restrict__ agg,
                               int e4) {
    int i = blockIdx.x * blockDim.x + threadIdx.x;
    const int stride = gridDim.x * blockDim.x;
    for (; i < e4; i += stride) {
        int4 rr = row4[i]; int4 cc = col4[i]; float4 ww = w4[i];
        atomicAdd(&agg[cc.x], log1pf(EPS - ww.x * x[rr.x]));
        atomicAdd(&agg[cc.y], log1pf(EPS - ww.y * x[rr.y]));
        atomicAdd(&agg[cc.z], log1pf(EPS - ww.z * x[rr.z]));
        atomicAdd(&agg[cc.w], log1pf(EPS - ww.w * x[rr.w]));
    }
}

__global__ void ic_node_kernel(float* __restrict__ s, float* __restrict__ x,
                               float* __restrict__ r, float* __restrict__ agg, int n) {
    const int i = blockIdx.x * blockDim.x + threadIdx.x;
    if (i < n) {
        const float q = expf(agg[i]);
        agg[i] = 0.0f;
        const float sv = s[i];
        const float xv = x[i];
        r[i] += xv;
        x[i] = sv * (1.0f - q);
        s[i] = sv * q;
    }
}

__global__ void ic_zero_kernel(float* __restrict__ p, int n) {
    const int i = blockIdx.x * blockDim.x + threadIdx.x;
    if (i < n) p[i] = 0.0f;
}

// ==================================== launch ====================================

extern "C" void kernel_launch(void* const* d_in, const int* in_sizes, int n_in,
                              void* d_out, int out_size, void* d_ws, size_t ws_size,
                              hipStream_t stream) {
    const int*   ei = (const int*)d_in[0];     // [2, E]: row then col
    const float* w  = (const float*)d_in[1];   // [E]
    const float* x0 = (const float*)d_in[2];   // [N]

    const int E = in_sizes[0] / 2;
    const int N = in_sizes[2];

    const int* row = ei;
    const int* col = ei + E;

    float* s = (float*)d_out;          // [0, N)
    float* xA = s + N;                 // [N, 2N)  (output x slot)
    float* r = s + 2 * N;              // [2N, 3N)

    const int B = (N + NPB - 1) / NPB; // buckets of 64 nodes

    // ws layout
    size_t o_rec = 0;
    size_t o_cnt = o_rec + (size_t)E * 8;
    size_t o_tot = o_cnt + (size_t)GC * B * 4;
    size_t o_base = o_tot + (size_t)B * 4;
    size_t o_xalt = o_base + (size_t)(B + 1) * 4 + 4;  // pad to 8B
    o_xalt = (o_xalt + 7) & ~(size_t)7;
    size_t need = o_xalt + (size_t)N * 4;

    const int nodeBlocks = (N + 255) / 256;

    if (ws_size >= need) {
        char* ws = (char*)d_ws;
        u64* rec = (u64*)(ws + o_rec);
        u32* cnt = (u32*)(ws + o_cnt);
        u32* totals = (u32*)(ws + o_tot);
        u32* base = (u32*)(ws + o_base);
        float* xB = (float*)(ws + o_xalt);

        ic_init_kernel<<<nodeBlocks, 256, 0, stream>>>(x0, s, xA, r, N);

        // Phase A: bucket counting sort (once per launch)
        ic_count_kernel<<<GC, 256, (size_t)B * 4, stream>>>(col, E, B, cnt);
        ic_scan_bucket_kernel<<<B, 256, 0, stream>>>(cnt, B, totals);
        ic_scan_base_kernel<<<1, 256, 0, stream>>>(totals, B, base, E);
        ic_scatter_kernel<<<GC, 256, (size_t)B * 4, stream>>>(row, col, w, cnt, base, E, B, rec);

        // Phase B: 10 fused steps, ping-pong x between xA (d_out) and xB (ws)
        for (int k = 0; k < 10; ++k) {
            const float* xin = (k & 1) ? xB : xA;
            float* xout = (k & 1) ? xA : xB;
            ic_step_kernel<<<B, 256, 0, stream>>>(rec, base, xin, xout, s, r, N);
        }
        // 10 steps: last write (k=9, odd) lands in xA = d_out. Done.
    } else {
        // Fallback: round-1 global-atomic path (needs only N floats of ws)
        float* agg = (float*)d_ws;
        ic_init_kernel<<<nodeBlocks, 256, 0, stream>>>(x0, s, xA, r, N);
        ic_zero_kernel<<<nodeBlocks, 256, 0, stream>>>(agg, N);
        const int e4 = E / 4;
        for (int step = 0; step < 10; ++step) {
            ic_edge_kernel<<<2048, 256, 0, stream>>>(
                (const int4*)row, (const int4*)col, (const float4*)w, xA, agg, e4);
            ic_node_kernel<<<nodeBlocks, 256, 0, stream>>>(s, xA, r, agg, N);
        }
    }
}